// Round 1
// baseline (289.448 us; speedup 1.0000x reference)
//
#include <hip/hip_runtime.h>

#define C_SEG 4096
#define E_CH 16
#define NE_EDGES 16384
#define P_PIX (1024 * 1024)

// ws layout (floats):
//   [0,      65536)  sums[C][E]
//   [65536,  69632)  counts[C]
//   [69632, 135168)  means[C][E]
//   [135168,139264)  inv_n[C]

// ---------------------------------------------------------------------------
// Kernel 1: segment sums + counts, LDS-privatized.
// grid = (64 pixel chunks, 5 groups). group 0: counts; group g in 1..4:
// channels (g-1)*4 .. (g-1)*4+3.  Each chunk = 16384 pixels.
// ---------------------------------------------------------------------------
__global__ __launch_bounds__(256) void k_segsum(const float* __restrict__ emb,
                                                const int* __restrict__ seg,
                                                float* __restrict__ sums,
                                                float* __restrict__ counts) {
    __shared__ float bins[C_SEG * 4];  // 64 KB
    const int g = blockIdx.y;
    const int t = threadIdx.x;
    const int base = blockIdx.x * 16384;

    for (int i = t; i < C_SEG * 4; i += 256) bins[i] = 0.0f;
    __syncthreads();

    if (g == 0) {
        // counts histogram (uses first 4096 bins)
        for (int it = 0; it < 16; ++it) {
            const int idx = base + (it * 256 + t) * 4;
            const int4 s4 = *(const int4*)(seg + idx);
            atomicAdd(&bins[s4.x], 1.0f);
            atomicAdd(&bins[s4.y], 1.0f);
            atomicAdd(&bins[s4.z], 1.0f);
            atomicAdd(&bins[s4.w], 1.0f);
        }
        __syncthreads();
        for (int i = t; i < C_SEG; i += 256) {
            const float v = bins[i];
            if (v != 0.0f) unsafeAtomicAdd(&counts[i], v);
        }
    } else {
        const int c0 = (g - 1) * 4;
        for (int it = 0; it < 16; ++it) {
            const int idx = base + (it * 256 + t) * 4;
            const int4 s4 = *(const int4*)(seg + idx);
#pragma unroll
            for (int c = 0; c < 4; ++c) {
                const float4 v =
                    *(const float4*)(emb + (size_t)(c0 + c) * P_PIX + idx);
                atomicAdd(&bins[s4.x * 4 + c], v.x);
                atomicAdd(&bins[s4.y * 4 + c], v.y);
                atomicAdd(&bins[s4.z * 4 + c], v.z);
                atomicAdd(&bins[s4.w * 4 + c], v.w);
            }
        }
        __syncthreads();
        for (int i = t; i < C_SEG * 4; i += 256) {
            const int s = i >> 2, c = i & 3;
            const float v = bins[i];
            if (v != 0.0f) unsafeAtomicAdd(&sums[s * E_CH + c0 + c], v);
        }
    }
}

// ---------------------------------------------------------------------------
// Kernel 2: means = sums / max(count,1); inv_n = 1/max(count,1)
// ---------------------------------------------------------------------------
__global__ __launch_bounds__(256) void k_means(const float* __restrict__ sums,
                                               const float* __restrict__ counts,
                                               float* __restrict__ means,
                                               float* __restrict__ inv_n) {
    const int i = blockIdx.x * 256 + threadIdx.x;  // 65536 total
    const int c = i >> 4;
    const float n = fmaxf(counts[c], 1.0f);
    means[i] = sums[i] / n;
    if ((i & 15) == 0) inv_n[c] = 1.0f / n;
}

__device__ __forceinline__ void block_reduce_atomic(float v, float scale,
                                                    float* out) {
    // 64-lane wave reduce
    for (int o = 32; o > 0; o >>= 1) v += __shfl_down(v, o, 64);
    __shared__ float wsum[4];
    const int t = threadIdx.x;
    if ((t & 63) == 0) wsum[t >> 6] = v;
    __syncthreads();
    if (t == 0) {
        const float b = wsum[0] + wsum[1] + wsum[2] + wsum[3];
        unsafeAtomicAdd(out, b * scale);
    }
}

// ---------------------------------------------------------------------------
// Kernel 3: intra term. 1 thread per pixel, 4096 blocks x 256.
// ---------------------------------------------------------------------------
__global__ __launch_bounds__(256) void k_intra(const float* __restrict__ emb,
                                               const int* __restrict__ seg,
                                               const float* __restrict__ means,
                                               const float* __restrict__ inv_n,
                                               float* __restrict__ out) {
    const int p = blockIdx.x * 256 + threadIdx.x;
    const int s = seg[p];
    const float4* mr = (const float4*)(means + s * E_CH);
    const float4 m0 = mr[0], m1 = mr[1], m2 = mr[2], m3 = mr[3];

    float dot = 0.0f;
    dot = fmaf(emb[(size_t)0 * P_PIX + p], m0.x, dot);
    dot = fmaf(emb[(size_t)1 * P_PIX + p], m0.y, dot);
    dot = fmaf(emb[(size_t)2 * P_PIX + p], m0.z, dot);
    dot = fmaf(emb[(size_t)3 * P_PIX + p], m0.w, dot);
    dot = fmaf(emb[(size_t)4 * P_PIX + p], m1.x, dot);
    dot = fmaf(emb[(size_t)5 * P_PIX + p], m1.y, dot);
    dot = fmaf(emb[(size_t)6 * P_PIX + p], m1.z, dot);
    dot = fmaf(emb[(size_t)7 * P_PIX + p], m1.w, dot);
    dot = fmaf(emb[(size_t)8 * P_PIX + p], m2.x, dot);
    dot = fmaf(emb[(size_t)9 * P_PIX + p], m2.y, dot);
    dot = fmaf(emb[(size_t)10 * P_PIX + p], m2.z, dot);
    dot = fmaf(emb[(size_t)11 * P_PIX + p], m2.w, dot);
    dot = fmaf(emb[(size_t)12 * P_PIX + p], m3.x, dot);
    dot = fmaf(emb[(size_t)13 * P_PIX + p], m3.y, dot);
    dot = fmaf(emb[(size_t)14 * P_PIX + p], m3.z, dot);
    dot = fmaf(emb[(size_t)15 * P_PIX + p], m3.w, dot);

    const float d = 1.0f - dot;
    const float v = fmaxf(d - 0.5f, 0.0f) * inv_n[s];
    block_reduce_atomic(v, 1.0f / (float)C_SEG, out);  // BETA=1, /C
}

// ---------------------------------------------------------------------------
// Kernel 4: inter term. 1 thread per edge, 64 blocks x 256.
// ---------------------------------------------------------------------------
__global__ __launch_bounds__(256) void k_inter(const int* __restrict__ edges,
                                               const float* __restrict__ w,
                                               const float* __restrict__ means,
                                               float* __restrict__ out) {
    const int i = blockIdx.x * 256 + threadIdx.x;  // 16384 total
    const int u = edges[i];
    const int v = edges[NE_EDGES + i];
    const float4* mu = (const float4*)(means + u * E_CH);
    const float4* mv = (const float4*)(means + v * E_CH);
    float dot = 0.0f;
#pragma unroll
    for (int q = 0; q < 4; ++q) {
        const float4 a = mu[q];
        const float4 b = mv[q];
        dot = fmaf(a.x, b.x, dot);
        dot = fmaf(a.y, b.y, dot);
        dot = fmaf(a.z, b.z, dot);
        dot = fmaf(a.w, b.w, dot);
    }
    const float d = 1.0f - dot;
    const float val = fmaxf(1.5f - d * w[i], 0.0f);
    block_reduce_atomic(val, 1.0f / (float)NE_EDGES, out);  // ALPHA=1, /Ne
}

extern "C" void kernel_launch(void* const* d_in, const int* in_sizes, int n_in,
                              void* d_out, int out_size, void* d_ws,
                              size_t ws_size, hipStream_t stream) {
    const float* emb = (const float*)d_in[0];      // (1,16,1024,1024) fp32
    const float* weights = (const float*)d_in[1];  // (16384,) fp32
    const int* seg = (const int*)d_in[2];          // (1,1,1024,1024) int32
    const int* edges = (const int*)d_in[3];        // (2,16384) int32
    float* out = (float*)d_out;

    float* ws = (float*)d_ws;
    float* sums = ws;            // 65536
    float* counts = ws + 65536;  // 4096
    float* means = ws + 69632;   // 65536
    float* invn = ws + 135168;   // 4096

    hipMemsetAsync(ws, 0, (65536 + 4096) * sizeof(float), stream);
    hipMemsetAsync(d_out, 0, sizeof(float), stream);

    dim3 g1(64, 5);
    k_segsum<<<g1, 256, 0, stream>>>(emb, seg, sums, counts);
    k_means<<<256, 256, 0, stream>>>(sums, counts, means, invn);
    k_intra<<<4096, 256, 0, stream>>>(emb, seg, means, invn, out);
    k_inter<<<64, 256, 0, stream>>>(edges, weights, means, out);
}